// Round 4
// baseline (74.600 us; speedup 1.0000x reference)
//
#include <hip/hip_runtime.h>

// Problem: B=8, C=64, W=256, H=256, fp32.
// out[b,c,w,h] = sig(Wc@mean_wh(x)+bc)[b,c] * sig(Ww@mean_ch(x)+bw)[b,w] * sig(Wh@mean_cw(x)+bh)[b,h]
// Memory-bound: read 134MB + write 134MB -> floor ~ 40-45us.
// R1: no atomics/reduces inside the load loop (in-order vmcnt).
// R2: out-writes evict x from L3 (134+134 > 256MB) -> nt stores for out;
//     use d_out head as partials scratch (no memset, no atomics).
// R4: pool 2048 blocks (32 waves/CU); fuse reduce+gates (3 dispatches);
//     out restructured so gate loads are loop-invariant / wave-uniform.

#define NB 8
#define NC 64
#define NW 256
#define NH 256

typedef float f4v __attribute__((ext_vector_type(4)));

// ws float layout: [4608,5120) gate_c  [5120,7168) gate_w  [7168,9216) gate_h
// d_out-head scratch (overwritten by out_kernel):
//   part_c [0,2048)            one per pool block
//   part_w [2048,133120)       [bc=512][w=256]
//   part_h [133120,657408)     [blk=2048][h=256]

__global__ __launch_bounds__(256) void pool_kernel(const float* __restrict__ x,
                                                   float* __restrict__ ps) {
    float* part_c = ps;
    float* part_w = ps + 2048;
    float* part_h = ps + 133120;

    int k    = blockIdx.x;         // 0..2047
    int bc   = k >> 2;             // b*64 + c
    int q    = k & 3;              // quarter (64 rows)
    int tid  = threadIdx.x;
    int wv   = tid >> 6;
    int lane = tid & 63;
    int wbase = q * 64;

    const float4* xr = (const float4*)x + (size_t)bc * (NW * (NH / 4));

    float4 col = make_float4(0.f, 0.f, 0.f, 0.f);
    __shared__ float rowsum[4][16];   // [wave][j] : row wbase + wv + 4j
    __shared__ float cols[4][NH];
    __shared__ float wpart[4];

    // wave wv owns rows wbase + wv + 4j, j=0..15; 8 loads in flight.
    for (int jb = 0; jb < 16; jb += 8) {
        float4 v[8];
        #pragma unroll
        for (int i = 0; i < 8; ++i)
            v[i] = xr[(wbase + wv + 4 * (jb + i)) * (NH / 4) + lane];
        float rs[8];
        #pragma unroll
        for (int i = 0; i < 8; ++i) {
            col.x += v[i].x; col.y += v[i].y; col.z += v[i].z; col.w += v[i].w;
            rs[i] = (v[i].x + v[i].y) + (v[i].z + v[i].w);
        }
        #pragma unroll
        for (int off = 32; off; off >>= 1) {
            #pragma unroll
            for (int i = 0; i < 8; ++i) rs[i] += __shfl_xor(rs[i], off);
        }
        #pragma unroll
        for (int i = 0; i < 8; ++i)
            if (lane == i) rowsum[wv][jb + i] = rs[i];
    }

    cols[wv][lane * 4 + 0] = col.x;
    cols[wv][lane * 4 + 1] = col.y;
    cols[wv][lane * 4 + 2] = col.z;
    cols[wv][lane * 4 + 3] = col.w;
    __syncthreads();

    float cv = cols[0][tid] + cols[1][tid] + cols[2][tid] + cols[3][tid];
    part_h[(size_t)k * 256 + tid] = cv;

    if (tid < 64)   // row r=tid of this quarter: rowsum[r&3][r>>2]
        part_w[(size_t)bc * 256 + wbase + tid] = rowsum[tid & 3][tid >> 2];

    float t = cv;
    #pragma unroll
    for (int off = 32; off; off >>= 1) t += __shfl_xor(t, off);
    if (lane == 0) wpart[wv] = t;
    __syncthreads();
    if (tid == 0) part_c[k] = wpart[0] + wpart[1] + wpart[2] + wpart[3];
}

// One block per batch b: reduce partials (to LDS) then compute all gates.
__global__ __launch_bounds__(256) void gates_kernel(const float* __restrict__ ps,
                                                    const float* __restrict__ Wc, const float* __restrict__ bc_,
                                                    const float* __restrict__ Ww, const float* __restrict__ bw_,
                                                    const float* __restrict__ Wh, const float* __restrict__ bh_,
                                                    float* __restrict__ ws) {
    const float* part_c = ps;
    const float* part_w = ps + 2048;
    const float* part_h = ps + 133120;
    float* gate_c = ws + 4608;
    float* gate_w = ws + 5120;
    float* gate_h = ws + 7168;

    int b = blockIdx.x, t = threadIdx.x;
    __shared__ float s_c[64], s_w[256], s_h[256];

    // sum_h[t] over 256 block-partials (16 loads in flight)
    {
        const float* p = part_h + (size_t)b * 256 * 256 + t;
        float s = 0.f;
        for (int jb = 0; jb < 256; jb += 16) {
            float v[16];
            #pragma unroll
            for (int i = 0; i < 16; ++i) v[i] = p[(jb + i) * 256];
            float s0 = 0.f, s1 = 0.f;
            #pragma unroll
            for (int i = 0; i < 16; i += 2) { s0 += v[i]; s1 += v[i + 1]; }
            s += s0 + s1;
        }
        s_h[t] = s;
    }
    // sum_w[t] over 64 c-partials
    {
        const float* p = part_w + (size_t)b * 64 * 256 + t;
        float s = 0.f;
        for (int jb = 0; jb < 64; jb += 16) {
            float v[16];
            #pragma unroll
            for (int i = 0; i < 16; ++i) v[i] = p[(jb + i) * 256];
            float s0 = 0.f, s1 = 0.f;
            #pragma unroll
            for (int i = 0; i < 16; i += 2) { s0 += v[i]; s1 += v[i + 1]; }
            s += s0 + s1;
        }
        s_w[t] = s;
    }
    // sum_c[t] (t<64) over 4 quarter-partials
    if (t < 64) {
        const float* p = part_c + (size_t)(b * 64 + t) * 4;
        s_c[t] = (p[0] + p[1]) + (p[2] + p[3]);
    }
    __syncthreads();

    const float4* sw4 = (const float4*)s_w;
    const float4* sh4 = (const float4*)s_h;
    const float4* sc4 = (const float4*)s_c;

    // gate_w[b,t] = sigmoid(dot(Ww[t,:], s_w)/16384 + bw[t])
    {
        const float4* wr = (const float4*)Ww + t * 64;
        float acc = 0.f;
        #pragma unroll 8
        for (int j = 0; j < 64; ++j) {
            float4 a = wr[j], s = sw4[j];
            acc += a.x * s.x + a.y * s.y + a.z * s.z + a.w * s.w;
        }
        gate_w[b * 256 + t] = 1.f / (1.f + expf(-(acc * (1.f / 16384.f) + bw_[t])));
    }
    // gate_h[b,t]
    {
        const float4* wr = (const float4*)Wh + t * 64;
        float acc = 0.f;
        #pragma unroll 8
        for (int j = 0; j < 64; ++j) {
            float4 a = wr[j], s = sh4[j];
            acc += a.x * s.x + a.y * s.y + a.z * s.z + a.w * s.w;
        }
        gate_h[b * 256 + t] = 1.f / (1.f + expf(-(acc * (1.f / 16384.f) + bh_[t])));
    }
    // gate_c[b,t] (t<64)
    if (t < 64) {
        const float4* wr = (const float4*)Wc + t * 16;
        float acc = 0.f;
        #pragma unroll 8
        for (int j = 0; j < 16; ++j) {
            float4 a = wr[j], s = sc4[j];
            acc += a.x * s.x + a.y * s.y + a.z * s.z + a.w * s.w;
        }
        gate_c[b * 64 + t] = 1.f / (1.f + expf(-(acc * (1.f / 65536.f) + bc_[t])));
    }
}

// Block k owns quarter q of slice bc: 4096 consecutive float4 (64KB).
// Per thread: gate_h4 & gate_c loop-invariant; gate_w wave-uniform, preloaded.
__global__ __launch_bounds__(256) void out_kernel(const float* __restrict__ ws,
                                                  float* __restrict__ out) {
    const float* gate_c = ws + 4608;
    const float* gate_w = ws + 5120;
    const float4* gate_h4 = (const float4*)(ws + 7168);

    int k  = blockIdx.x;          // 0..2047
    int bc = k >> 2;
    int q  = k & 3;
    int b  = bc >> 6;
    int t  = threadIdx.x;
    int h4 = t & 63;
    int wv = t >> 6;

    float gc = gate_c[bc];
    float4 gh = gate_h4[b * 64 + h4];

    float gw[16];
    #pragma unroll
    for (int kk = 0; kk < 16; ++kk)
        gw[kk] = gate_w[b * 256 + q * 64 + wv + 4 * kk];

    float4* dst = (float4*)out + (size_t)bc * 16384 + q * 4096 + t;
    #pragma unroll
    for (int kk = 0; kk < 16; ++kk) {
        float g = gc * gw[kk];
        f4v val = {g * gh.x, g * gh.y, g * gh.z, g * gh.w};
        __builtin_nontemporal_store(val, (f4v*)(dst + 256 * kk));
    }
}

extern "C" void kernel_launch(void* const* d_in, const int* in_sizes, int n_in,
                              void* d_out, int out_size, void* d_ws, size_t ws_size,
                              hipStream_t stream) {
    const float* x   = (const float*)d_in[0];
    const float* Wc  = (const float*)d_in[1];
    const float* bc_ = (const float*)d_in[2];
    const float* Ww  = (const float*)d_in[3];
    const float* bw_ = (const float*)d_in[4];
    const float* Wh  = (const float*)d_in[5];
    const float* bh_ = (const float*)d_in[6];
    float* ws = (float*)d_ws;
    float* ps = (float*)d_out;   // head of d_out = partials scratch

    pool_kernel<<<2048, 256, 0, stream>>>(x, ps);
    gates_kernel<<<NB, 256, 0, stream>>>(ps, Wc, bc_, Ww, bw_, Wh, bh_, ws);
    out_kernel<<<2048, 256, 0, stream>>>(ws, (float*)d_out);
}

// Round 5
// 62.801 us; speedup vs baseline: 1.1879x; 1.1879x over previous
//
#include <hip/hip_runtime.h>

// Problem: B=8, C=64, W=256, H=256, fp32.
// out[b,c,w,h] = sig(Wc@mean_wh(x)+bc)[b,c] * sig(Ww@mean_ch(x)+bw)[b,w] * sig(Wh@mean_cw(x)+bh)[b,h]
// Memory-bound: read 134MB + write 134MB -> floor ~46us incl. boundaries.
// R1: no atomics/reduces inside the load loop (in-order vmcnt).
// R2: out-writes evict x from L3 (memory-side MALL always allocates) -> x reads
//     come from HBM each replay; nt stores neutral but harmless, keep them.
// R4 lesson: NEVER reduce grid-wide-written partials with few (8) blocks --
//     cross-XCD dirty-L2 reads serialize (+16us). Block-end atomics are free.
// R5: A/B on pool only: 2048 blocks, 16 loads in flight, block-end atomics.

#define NB 8
#define NC 64
#define NW 256
#define NH 256

typedef float f4v __attribute__((ext_vector_type(4)));

// ws float layout:
// [0,512)      sum_c   [512,2560) sum_w   [2560,4608) sum_h   (atomic, memset each call)
// [4608,5120)  gate_c  [5120,7168) gate_w [7168,9216) gate_h

__global__ __launch_bounds__(256) void pool_kernel(const float* __restrict__ x,
                                                   float* __restrict__ ws) {
    float* sum_c = ws;
    float* sum_w = ws + 512;
    float* sum_h = ws + 2560;

    int k    = blockIdx.x;         // 0..2047
    int bc   = k >> 2;             // b*64 + c
    int q    = k & 3;              // quarter: rows [q*64, q*64+64)
    int b    = bc >> 6;
    int tid  = threadIdx.x;
    int wv   = tid >> 6;           // wave 0..3
    int lane = tid & 63;

    // wave wv owns 16 contiguous rows: q*64 + wv*16 + r, r=0..15
    const f4v* xr = (const f4v*)x + (size_t)bc * (NW * (NH / 4))
                    + (size_t)(q * 64 + wv * 16) * (NH / 4) + lane;

    __shared__ float rowsum[4][16];
    __shared__ float cols[4][NH];
    __shared__ float wpart[4];

    // all 16 loads issued before any dependent VALU
    f4v v[16];
    #pragma unroll
    for (int r = 0; r < 16; ++r) v[r] = xr[(size_t)r * (NH / 4)];

    f4v col = {0.f, 0.f, 0.f, 0.f};
    float rs[16];
    #pragma unroll
    for (int r = 0; r < 16; ++r) {
        col += v[r];
        rs[r] = (v[r][0] + v[r][1]) + (v[r][2] + v[r][3]);
    }
    // 16 independent butterfly chains
    #pragma unroll
    for (int off = 32; off; off >>= 1) {
        #pragma unroll
        for (int r = 0; r < 16; ++r) rs[r] += __shfl_xor(rs[r], off);
    }
    #pragma unroll
    for (int r = 0; r < 16; ++r)
        if (lane == r) rowsum[wv][r] = rs[r];

    cols[wv][lane * 4 + 0] = col[0];
    cols[wv][lane * 4 + 1] = col[1];
    cols[wv][lane * 4 + 2] = col[2];
    cols[wv][lane * 4 + 3] = col[3];
    __syncthreads();

    // h-partials: thread t owns column h=t; one coalesced atomic per thread
    float cv = cols[0][tid] + cols[1][tid] + cols[2][tid] + cols[3][tid];
    atomicAdd(&sum_h[b * NH + tid], cv);

    // row sums: local row r=tid (0..63) -> wave tid>>4, slot tid&15
    if (tid < 64)
        atomicAdd(&sum_w[b * NW + q * 64 + tid], rowsum[tid >> 4][tid & 15]);

    // block total -> sum_c
    float t = cv;
    #pragma unroll
    for (int off = 32; off; off >>= 1) t += __shfl_xor(t, off);
    if (lane == 0) wpart[wv] = t;
    __syncthreads();
    if (tid == 0) atomicAdd(&sum_c[bc], wpart[0] + wpart[1] + wpart[2] + wpart[3]);
}

__global__ __launch_bounds__(256) void gates_kernel(const float* __restrict__ Wc, const float* __restrict__ bc_,
                                                    const float* __restrict__ Ww, const float* __restrict__ bw_,
                                                    const float* __restrict__ Wh, const float* __restrict__ bh_,
                                                    float* __restrict__ ws) {
    const float* sum_c = ws;
    const float* sum_w = ws + 512;
    const float* sum_h = ws + 2560;
    float* gate_c = ws + 4608;
    float* gate_w = ws + 5120;
    float* gate_h = ws + 7168;

    int j = blockIdx.x * 4 + (threadIdx.x >> 6);  // global wave id, 0..4607
    int lane = threadIdx.x & 63;

    float acc = 0.f, bias;
    float* dst;
    if (j < 512) {                                 // c-gate: dot length 64
        int b = j >> 6, o = j & 63;
        acc = Wc[o * 64 + lane] * sum_c[b * 64 + lane] * (1.f / 65536.f);
        bias = bc_[o];
        dst = &gate_c[j];
    } else if (j < 2560) {                         // w-gate: dot length 256
        int j2 = j - 512;
        int b = j2 >> 8, o = j2 & 255;
        const float* wr = Ww + o * 256;
        const float* sr = sum_w + b * 256;
        #pragma unroll
        for (int m = 0; m < 4; ++m) acc += wr[lane + 64 * m] * sr[lane + 64 * m];
        acc *= (1.f / 16384.f);
        bias = bw_[o];
        dst = &gate_w[j2];
    } else {                                       // h-gate: dot length 256
        int j2 = j - 2560;
        int b = j2 >> 8, o = j2 & 255;
        const float* wr = Wh + o * 256;
        const float* sr = sum_h + b * 256;
        #pragma unroll
        for (int m = 0; m < 4; ++m) acc += wr[lane + 64 * m] * sr[lane + 64 * m];
        acc *= (1.f / 16384.f);
        bias = bh_[o];
        dst = &gate_h[j2];
    }
    #pragma unroll
    for (int off = 32; off; off >>= 1) acc += __shfl_xor(acc, off);
    if (lane == 0) *dst = 1.f / (1.f + expf(-(acc + bias)));
}

__global__ __launch_bounds__(256) void out_kernel(const float* __restrict__ ws,
                                                  float* __restrict__ out) {
    const float* gate_c = ws + 4608;
    const float* gate_w = ws + 5120;
    const float4* gate_h4 = (const float4*)(ws + 7168);

    const size_t N4 = (size_t)NB * NC * NW * (NH / 4);  // 8388608
    size_t stride = (size_t)gridDim.x * blockDim.x;
    for (size_t i = (size_t)blockIdx.x * blockDim.x + threadIdx.x; i < N4; i += stride) {
        int h4 = (int)(i & 63);          // H/4 = 64
        size_t row = i >> 6;
        int w = (int)(row & 255);        // W = 256
        size_t bcr = row >> 8;
        int c = (int)(bcr & 63);         // C = 64
        int b = (int)(bcr >> 6);
        float g = gate_c[b * 64 + c] * gate_w[b * 256 + w];
        float4 gh = gate_h4[b * 64 + h4];
        f4v val = {g * gh.x, g * gh.y, g * gh.z, g * gh.w};
        // non-temporal: keep L2 clean (L3 allocates regardless)
        __builtin_nontemporal_store(val, (f4v*)(out + 4 * i));
    }
}

extern "C" void kernel_launch(void* const* d_in, const int* in_sizes, int n_in,
                              void* d_out, int out_size, void* d_ws, size_t ws_size,
                              hipStream_t stream) {
    const float* x   = (const float*)d_in[0];
    const float* Wc  = (const float*)d_in[1];
    const float* bc_ = (const float*)d_in[2];
    const float* Ww  = (const float*)d_in[3];
    const float* bw_ = (const float*)d_in[4];
    const float* Wh  = (const float*)d_in[5];
    const float* bh_ = (const float*)d_in[6];
    float* ws = (float*)d_ws;

    // zero the atomic accumulators (sum_c, sum_w, sum_h)
    hipMemsetAsync(ws, 0, 4608 * sizeof(float), stream);

    pool_kernel<<<2048, 256, 0, stream>>>(x, ws);
    gates_kernel<<<4608 / 4, 256, 0, stream>>>(Wc, bc_, Ww, bw_, Wh, bh_, ws);
    out_kernel<<<2048, 256, 0, stream>>>(ws, (float*)d_out);
}